// Round 12
// baseline (155.010 us; speedup 1.0000x reference)
//
#include <hip/hip_runtime.h>
#include <math.h>

#define ALPHA_F 0.02f

constexpr int Bn  = 32;
constexpr int Cn  = 512;
constexpr int CRn = 32;    // C / 16
constexpr int HWn = 4096;  // 64*64
constexpr int NCG = 8;     // channel groups of 64 channels
constexpr int NPG = 8;     // K1 pixel groups of 512 pixels (was 4x1024)

typedef float floatx4 __attribute__((ext_vector_type(4)));

__device__ __forceinline__ float sigmoidf_(float v) {
    return 1.0f / (1.0f + expf(-v));
}

// ---------------------------------------------------------------------------
// K1: one pass over x. 512-pixel groups -> 2048 blocks = 8 blocks/CU
// (2x the waves of the 1024-px version; K1 was occupancy/latency-bound:
// VALUBusy 15%, HBM 33%, occupancy 24.8% grid-capped at 4 blocks/CU).
// Reduction structure unchanged (R9/R10: restructures regress).
// Block = (b, cg, pg): 64 channels x 512 pixels. 4 waves; wave owns 16 chans.
// ---------------------------------------------------------------------------
__global__ __launch_bounds__(256) void k1_reduce(
    const float* __restrict__ x,
    float* __restrict__ cps, float* __restrict__ cpm,
    float* __restrict__ sps, float* __restrict__ spm)
{
    const int bid = blockIdx.x;
    const int pg  = bid & 7;
    const int cg  = (bid >> 3) & 7;
    const int b   = bid >> 6;
    const int t    = threadIdx.x;
    const int wv   = t >> 6;
    const int lane = t & 63;

    __shared__ float ls[4][512];
    __shared__ float lm[4][512];

    const float* xb = x + ((size_t)b * Cn + (size_t)cg * 64) * HWn + pg * 512;

    // per-pixel accumulators: 512 px = 2 float4 per lane
    float4 psum[2], pmax[2];
#pragma unroll
    for (int q = 0; q < 2; ++q) {
        psum[q] = make_float4(0.f, 0.f, 0.f, 0.f);
        pmax[q] = make_float4(-INFINITY, -INFINITY, -INFINITY, -INFINITY);
    }

#pragma unroll 4
    for (int cl = 0; cl < 16; ++cl) {
        const int c = wv * 16 + cl;  // channel within the 64-ch group
        const float4* row = (const float4*)(xb + (size_t)c * HWn);
        float lsum = 0.f, lmax = -INFINITY;
#pragma unroll
        for (int q = 0; q < 2; ++q) {
            const float4 v = row[q * 64 + lane];
            psum[q].x += v.x; psum[q].y += v.y; psum[q].z += v.z; psum[q].w += v.w;
            pmax[q].x = fmaxf(pmax[q].x, v.x);
            pmax[q].y = fmaxf(pmax[q].y, v.y);
            pmax[q].z = fmaxf(pmax[q].z, v.z);
            pmax[q].w = fmaxf(pmax[q].w, v.w);
            lsum += (v.x + v.y) + (v.z + v.w);
            lmax = fmaxf(lmax, fmaxf(fmaxf(v.x, v.y), fmaxf(v.z, v.w)));
        }
        // wave-level reduce over 64 lanes -> partial over 512 pixels
#pragma unroll
        for (int m = 32; m >= 1; m >>= 1) {
            lsum += __shfl_xor(lsum, m, 64);
            lmax = fmaxf(lmax, __shfl_xor(lmax, m, 64));
        }
        if (lane == 0) {
            const int cglob = cg * 64 + c;
            cps[(pg * Bn + b) * Cn + cglob] = lsum;
            cpm[(pg * Bn + b) * Cn + cglob] = lmax;
        }
    }

    // stash per-wave pixel partials, combine across the 4 waves
    float4* lsw = (float4*)ls[wv];
    float4* lmw = (float4*)lm[wv];
#pragma unroll
    for (int q = 0; q < 2; ++q) {
        lsw[q * 64 + lane] = psum[q];
        lmw[q * 64 + lane] = pmax[q];
    }
    __syncthreads();

    if (t < 128) {  // 512 px = 128 float4
        float4 s  = ((const float4*)ls[0])[t];
        float4 mx = ((const float4*)lm[0])[t];
#pragma unroll
        for (int w = 1; w < 4; ++w) {
            const float4 a  = ((const float4*)ls[w])[t];
            const float4 bb = ((const float4*)lm[w])[t];
            s.x += a.x; s.y += a.y; s.z += a.z; s.w += a.w;
            mx.x = fmaxf(mx.x, bb.x); mx.y = fmaxf(mx.y, bb.y);
            mx.z = fmaxf(mx.z, bb.z); mx.w = fmaxf(mx.w, bb.w);
        }
        float4* os = (float4*)(sps + ((size_t)cg * Bn + b) * HWn + pg * 512);
        float4* om = (float4*)(spm + ((size_t)cg * Bn + b) * HWn + pg * 512);
        os[t] = s;
        om[t] = mx;
    }
}

// ---------------------------------------------------------------------------
// K_mid (fused): grid = 32 batches x 8 pixel-slices, 256 threads.
// Each block: halo-finalize a 14-row window of spatial partials into LDS,
// 7x7-conv its own 8 rows -> msF. Slice-0 blocks additionally run the
// channel MLP -> mcF (block-uniform branch). NPG=8 channel partials.
// ---------------------------------------------------------------------------
__global__ __launch_bounds__(256) void k_mid(
    const float* __restrict__ sps, const float* __restrict__ spm,
    const float* __restrict__ cps, const float* __restrict__ cpm,
    const float* __restrict__ w1, const float* __restrict__ w2,
    const float* __restrict__ wconv,
    float* __restrict__ mcF, float* __restrict__ msF)
{
    const int b = blockIdx.x >> 3;
    const int s = blockIdx.x & 7;   // pixel slice: own rows [8s, 8s+8)
    const int t = threadIdx.x;

    __shared__ float wsa[14][64];
    __shared__ float wsm[14][64];
    __shared__ float avg[Cn];
    __shared__ float mxv[Cn];
    __shared__ float hs[CRn];
    __shared__ float wc[98];
    if (t < 98) wc[t] = wconv[t];

    // A) halo finalize: window rows yw in [8s-3, 8s+11), 14 rows x 64 cols
    const int ybase = s * 8 - 3;
    {
        const int cgstep = Bn * HWn;  // float stride between cg planes
        const float inv = 1.0f / (float)Cn;
#pragma unroll
        for (int k = 0; k < 4; ++k) {
            const int i = t + 256 * k;       // 0..895 window-local px
            if (i < 14 * 64) {
                const int rw  = i >> 6;
                const int col = i & 63;
                const int yw  = ybase + rw;
                if ((unsigned)yw < 64u) {
                    const int p = (yw << 6) + col;
                    const float* ps = sps + (size_t)b * HWn + p;
                    const float* pm = spm + (size_t)b * HWn + p;
                    float sv = ps[0], mv = pm[0];
#pragma unroll
                    for (int cg = 1; cg < NCG; ++cg) {
                        sv += ps[(size_t)cg * cgstep];
                        mv = fmaxf(mv, pm[(size_t)cg * cgstep]);
                    }
                    wsa[rw][col] = sv * inv;
                    wsm[rw][col] = mv;
                } else {
                    wsa[rw][col] = 0.f;
                    wsm[rw][col] = 0.f;
                }
            }
        }
    }

    // B) channel MLP, slice-0 blocks only (block-uniform condition)
    if (s == 0) {
        for (int c = t; c < Cn; c += 256) {
            float sv = 0.f, mv = -INFINITY;
#pragma unroll
            for (int pgi = 0; pgi < NPG; ++pgi) {
                sv += cps[(pgi * Bn + b) * Cn + c];
                mv = fmaxf(mv, cpm[(pgi * Bn + b) * Cn + c]);
            }
            avg[c] = sv * (1.0f / (float)HWn);
            mxv[c] = mv;
        }
        __syncthreads();

        const int j = t >> 3, s8 = t & 7;
        float pa = 0.f, pm2 = 0.f;
        const float* w1r = w1 + j * Cn + s8 * 64;
        const float* av  = avg + s8 * 64;
        const float* mv  = mxv + s8 * 64;
        for (int k = 0; k < 64; ++k) {
            pa  += av[k] * w1r[k];
            pm2 += mv[k] * w1r[k];
        }
        pa += __shfl_xor(pa, 1, 64); pm2 += __shfl_xor(pm2, 1, 64);
        pa += __shfl_xor(pa, 2, 64); pm2 += __shfl_xor(pm2, 2, 64);
        pa += __shfl_xor(pa, 4, 64); pm2 += __shfl_xor(pm2, 4, 64);
        if (s8 == 0) hs[j] = fmaxf(pa, 0.f) + fmaxf(pm2, 0.f);
        __syncthreads();

        for (int c = t; c < Cn; c += 256) {
            float o = 0.f;
            const float* w2r = w2 + c * CRn;
#pragma unroll
            for (int jj = 0; jj < CRn; ++jj) o += hs[jj] * w2r[jj];
            mcF[b * Cn + c] = 1.0f - ALPHA_F + ALPHA_F * sigmoidf_(o);
        }
    } else {
        __syncthreads();
        __syncthreads();
    }
    __syncthreads();

    // C) 7x7 conv over own 8 rows (512 px, 2 per thread) from LDS window
#pragma unroll
    for (int k = 0; k < 2; ++k) {
        const int pl  = t + 256 * k;        // 0..511 own-local px
        const int ry  = pl >> 6;            // own row 0..7
        const int col = pl & 63;
        const int yown = s * 8 + ry;
        float acc = 0.f;
#pragma unroll
        for (int ky = 0; ky < 7; ++ky) {
            const int yy = yown + ky - 3;
            if ((unsigned)yy >= 64u) continue;
            const int rw = ry + ky;         // yy - ybase
#pragma unroll
            for (int kx = 0; kx < 7; ++kx) {
                const int xx = col + kx - 3;
                if ((unsigned)xx >= 64u) continue;
                acc += wc[ky * 7 + kx] * wsa[rw][xx]
                     + wc[49 + ky * 7 + kx] * wsm[rw][xx];
            }
        }
        msF[b * HWn + (yown << 6) + col] = 1.0f - ALPHA_F + ALPHA_F * sigmoidf_(acc);
    }
}

// ---------------------------------------------------------------------------
// K4: out = x * mcF[b,c] * msF[b,p]. (b,cg,pg4) 1024-px chunk mapping;
// NT stores keep x L3-resident. Measured ~7.5 TB/s combined — at ceiling.
// UNCHANGED from the proven R7/R11 version.
// ---------------------------------------------------------------------------
__global__ __launch_bounds__(256) void k4_apply(
    const float* __restrict__ x, const float* __restrict__ mcF,
    const float* __restrict__ msF, float* __restrict__ out)
{
    const int bid = blockIdx.x;
    const int pg  = bid & 3;
    const int cg  = (bid >> 2) & 7;
    const int b   = bid >> 5;
    const int t   = threadIdx.x;

    const size_t chunk_off = ((size_t)b * Cn + (size_t)cg * 64) * HWn + pg * 1024;
    const float* xb = x + chunk_off;
    float* ob = out + chunk_off;

    const floatx4 msv = ((const floatx4*)(msF + (size_t)b * HWn + pg * 1024))[t];
    const float* mcRow = mcF + b * Cn + cg * 64;

#pragma unroll 8
    for (int r = 0; r < 64; ++r) {
        const floatx4 xv = ((const floatx4*)(xb + (size_t)r * HWn))[t];
        const floatx4 res = xv * (mcRow[r] * msv);
        __builtin_nontemporal_store(res, ((floatx4*)(ob + (size_t)r * HWn)) + t);
    }
}

extern "C" void kernel_launch(void* const* d_in, const int* in_sizes, int n_in,
                              void* d_out, int out_size, void* d_ws, size_t ws_size,
                              hipStream_t stream)
{
    const float* x     = (const float*)d_in[0];
    const float* w1    = (const float*)d_in[1];
    const float* w2    = (const float*)d_in[2];
    const float* wconv = (const float*)d_in[3];
    float* out = (float*)d_out;

    float* p = (float*)d_ws;
    float* cps  = p; p += NPG * Bn * Cn;   // 131072
    float* cpm  = p; p += NPG * Bn * Cn;   // 131072
    float* sps  = p; p += NCG * Bn * HWn;  // 1048576
    float* spm  = p; p += NCG * Bn * HWn;  // 1048576
    float* mcF  = p; p += Bn * Cn;         // 16384
    float* msF  = p; p += Bn * HWn;        // 131072

    hipLaunchKernelGGL(k1_reduce, dim3(Bn * NCG * NPG), dim3(256), 0, stream,
                       x, cps, cpm, sps, spm);
    hipLaunchKernelGGL(k_mid, dim3(Bn * 8), dim3(256), 0, stream,
                       sps, spm, cps, cpm, w1, w2, wconv, mcF, msF);
    hipLaunchKernelGGL(k4_apply, dim3(Bn * NCG * 4), dim3(256), 0, stream,
                       x, mcF, msF, out);
}

// Round 13
// 150.660 us; speedup vs baseline: 1.0289x; 1.0289x over previous
//
#include <hip/hip_runtime.h>
#include <math.h>

#define ALPHA_F 0.02f

constexpr int Bn  = 32;
constexpr int Cn  = 512;
constexpr int CRn = 32;    // C / 16
constexpr int HWn = 4096;  // 64*64
constexpr int NCG = 8;     // channel groups of 64 channels
constexpr int NPG = 4;     // pixel groups of 1024 pixels

typedef float floatx4 __attribute__((ext_vector_type(4)));

__device__ __forceinline__ float sigmoidf_(float v) {
    return 1.0f / (1.0f + expf(-v));
}

// ---------------------------------------------------------------------------
// K1: one pass over x. Computes
//   cps/cpm: channel partial sum/max  [NPG][B][C]   (partial over 1024 pixels)
//   sps/spm: spatial partial sum/max  [NCG][B][HW]  (partial over 64 channels)
// Block = (b, cg, pg): 64 channels x 1024 pixels. 4 waves; wave owns 16 chans.
// Lever sweep complete: serial shuffles [best] / interleaved [-15us] /
// LDS-transpose [-5us] / 2x occupancy [-2us]. 4.8 TB/s read is the
// structural limit for this access pattern.
// ---------------------------------------------------------------------------
__global__ __launch_bounds__(256) void k1_reduce(
    const float* __restrict__ x,
    float* __restrict__ cps, float* __restrict__ cpm,
    float* __restrict__ sps, float* __restrict__ spm)
{
    const int bid = blockIdx.x;
    const int pg  = bid & 3;
    const int cg  = (bid >> 2) & 7;
    const int b   = bid >> 5;
    const int t    = threadIdx.x;
    const int wv   = t >> 6;
    const int lane = t & 63;

    __shared__ float ls[4][1024];
    __shared__ float lm[4][1024];

    const float* xb = x + ((size_t)b * Cn + (size_t)cg * 64) * HWn + pg * 1024;

    // per-pixel accumulators: pixel_local = 256*q + 4*lane + i
    float4 psum[4], pmax[4];
#pragma unroll
    for (int q = 0; q < 4; ++q) {
        psum[q] = make_float4(0.f, 0.f, 0.f, 0.f);
        pmax[q] = make_float4(-INFINITY, -INFINITY, -INFINITY, -INFINITY);
    }

#pragma unroll 4
    for (int cl = 0; cl < 16; ++cl) {
        const int c = wv * 16 + cl;  // channel within the 64-ch group
        const float4* row = (const float4*)(xb + (size_t)c * HWn);
        float lsum = 0.f, lmax = -INFINITY;
#pragma unroll
        for (int q = 0; q < 4; ++q) {
            const float4 v = row[q * 64 + lane];
            psum[q].x += v.x; psum[q].y += v.y; psum[q].z += v.z; psum[q].w += v.w;
            pmax[q].x = fmaxf(pmax[q].x, v.x);
            pmax[q].y = fmaxf(pmax[q].y, v.y);
            pmax[q].z = fmaxf(pmax[q].z, v.z);
            pmax[q].w = fmaxf(pmax[q].w, v.w);
            lsum += (v.x + v.y) + (v.z + v.w);
            lmax = fmaxf(lmax, fmaxf(fmaxf(v.x, v.y), fmaxf(v.z, v.w)));
        }
        // wave-level reduce over 64 lanes -> partial over 1024 pixels
#pragma unroll
        for (int m = 32; m >= 1; m >>= 1) {
            lsum += __shfl_xor(lsum, m, 64);
            lmax = fmaxf(lmax, __shfl_xor(lmax, m, 64));
        }
        if (lane == 0) {
            const int cglob = cg * 64 + c;
            cps[(pg * Bn + b) * Cn + cglob] = lsum;
            cpm[(pg * Bn + b) * Cn + cglob] = lmax;
        }
    }

    // stash per-wave pixel partials, combine across the 4 waves
    float4* lsw = (float4*)ls[wv];
    float4* lmw = (float4*)lm[wv];
#pragma unroll
    for (int q = 0; q < 4; ++q) {
        lsw[q * 64 + lane] = psum[q];
        lmw[q * 64 + lane] = pmax[q];
    }
    __syncthreads();

    float4 s  = ((const float4*)ls[0])[t];
    float4 mx = ((const float4*)lm[0])[t];
#pragma unroll
    for (int w = 1; w < 4; ++w) {
        const float4 a  = ((const float4*)ls[w])[t];
        const float4 bb = ((const float4*)lm[w])[t];
        s.x += a.x; s.y += a.y; s.z += a.z; s.w += a.w;
        mx.x = fmaxf(mx.x, bb.x); mx.y = fmaxf(mx.y, bb.y);
        mx.z = fmaxf(mx.z, bb.z); mx.w = fmaxf(mx.w, bb.w);
    }
    float4* os = (float4*)(sps + ((size_t)cg * Bn + b) * HWn + pg * 1024);
    float4* om = (float4*)(spm + ((size_t)cg * Bn + b) * HWn + pg * 1024);
    os[t] = s;
    om[t] = mx;
}

// ---------------------------------------------------------------------------
// K_mid (fused k2a+k2b+k3): grid = 32 batches x 8 pixel-slices, 256 threads.
// Each block: halo-finalize a 14-row window of spatial partials into LDS,
// 7x7-conv its own 8 rows -> msF. Slice-0 blocks additionally run the
// channel MLP -> mcF (block-uniform branch).
// ---------------------------------------------------------------------------
__global__ __launch_bounds__(256) void k_mid(
    const float* __restrict__ sps, const float* __restrict__ spm,
    const float* __restrict__ cps, const float* __restrict__ cpm,
    const float* __restrict__ w1, const float* __restrict__ w2,
    const float* __restrict__ wconv,
    float* __restrict__ mcF, float* __restrict__ msF)
{
    const int b = blockIdx.x >> 3;
    const int s = blockIdx.x & 7;   // pixel slice: own rows [8s, 8s+8)
    const int t = threadIdx.x;

    __shared__ float wsa[14][64];
    __shared__ float wsm[14][64];
    __shared__ float avg[Cn];
    __shared__ float mxv[Cn];
    __shared__ float hs[CRn];
    __shared__ float wc[98];
    if (t < 98) wc[t] = wconv[t];

    // A) halo finalize: window rows yw in [8s-3, 8s+11), 14 rows x 64 cols
    const int ybase = s * 8 - 3;
    {
        const int cgstep = Bn * HWn;  // float stride between cg planes
        const float inv = 1.0f / (float)Cn;
#pragma unroll
        for (int k = 0; k < 4; ++k) {
            const int i = t + 256 * k;       // 0..895 window-local px
            if (i < 14 * 64) {
                const int rw  = i >> 6;
                const int col = i & 63;
                const int yw  = ybase + rw;
                if ((unsigned)yw < 64u) {
                    const int p = (yw << 6) + col;
                    const float* ps = sps + (size_t)b * HWn + p;
                    const float* pm = spm + (size_t)b * HWn + p;
                    float sv = ps[0], mv = pm[0];
#pragma unroll
                    for (int cg = 1; cg < NCG; ++cg) {
                        sv += ps[(size_t)cg * cgstep];
                        mv = fmaxf(mv, pm[(size_t)cg * cgstep]);
                    }
                    wsa[rw][col] = sv * inv;
                    wsm[rw][col] = mv;
                } else {
                    wsa[rw][col] = 0.f;
                    wsm[rw][col] = 0.f;
                }
            }
        }
    }

    // B) channel MLP, slice-0 blocks only (block-uniform condition)
    if (s == 0) {
        for (int c = t; c < Cn; c += 256) {
            float sv = 0.f, mv = -INFINITY;
#pragma unroll
            for (int pgi = 0; pgi < NPG; ++pgi) {
                sv += cps[(pgi * Bn + b) * Cn + c];
                mv = fmaxf(mv, cpm[(pgi * Bn + b) * Cn + c]);
            }
            avg[c] = sv * (1.0f / (float)HWn);
            mxv[c] = mv;
        }
        __syncthreads();

        const int j = t >> 3, s8 = t & 7;
        float pa = 0.f, pm2 = 0.f;
        const float* w1r = w1 + j * Cn + s8 * 64;
        const float* av  = avg + s8 * 64;
        const float* mv  = mxv + s8 * 64;
        for (int k = 0; k < 64; ++k) {
            pa  += av[k] * w1r[k];
            pm2 += mv[k] * w1r[k];
        }
        pa += __shfl_xor(pa, 1, 64); pm2 += __shfl_xor(pm2, 1, 64);
        pa += __shfl_xor(pa, 2, 64); pm2 += __shfl_xor(pm2, 2, 64);
        pa += __shfl_xor(pa, 4, 64); pm2 += __shfl_xor(pm2, 4, 64);
        if (s8 == 0) hs[j] = fmaxf(pa, 0.f) + fmaxf(pm2, 0.f);
        __syncthreads();

        for (int c = t; c < Cn; c += 256) {
            float o = 0.f;
            const float* w2r = w2 + c * CRn;
#pragma unroll
            for (int jj = 0; jj < CRn; ++jj) o += hs[jj] * w2r[jj];
            mcF[b * Cn + c] = 1.0f - ALPHA_F + ALPHA_F * sigmoidf_(o);
        }
    } else {
        __syncthreads();
        __syncthreads();
    }
    __syncthreads();

    // C) 7x7 conv over own 8 rows (512 px, 2 per thread) from LDS window
#pragma unroll
    for (int k = 0; k < 2; ++k) {
        const int pl  = t + 256 * k;        // 0..511 own-local px
        const int ry  = pl >> 6;            // own row 0..7
        const int col = pl & 63;
        const int yown = s * 8 + ry;
        float acc = 0.f;
#pragma unroll
        for (int ky = 0; ky < 7; ++ky) {
            const int yy = yown + ky - 3;
            if ((unsigned)yy >= 64u) continue;
            const int rw = ry + ky;         // yy - ybase
#pragma unroll
            for (int kx = 0; kx < 7; ++kx) {
                const int xx = col + kx - 3;
                if ((unsigned)xx >= 64u) continue;
                acc += wc[ky * 7 + kx] * wsa[rw][xx]
                     + wc[49 + ky * 7 + kx] * wsm[rw][xx];
            }
        }
        msF[b * HWn + (yown << 6) + col] = 1.0f - ALPHA_F + ALPHA_F * sigmoidf_(acc);
    }
}

// ---------------------------------------------------------------------------
// K4: out = x * mcF[b,c] * msF[b,p]. Same (b,cg,pg) chunk mapping as K1 so
// the block re-reads what its XCD's L2/L3 already holds; NT stores so `out`
// doesn't evict x (x = 256 MB = exactly the Infinity Cache).
// Measured ~7.5 TB/s combined R+W (R8 mega) — at the streaming ceiling.
// ---------------------------------------------------------------------------
__global__ __launch_bounds__(256) void k4_apply(
    const float* __restrict__ x, const float* __restrict__ mcF,
    const float* __restrict__ msF, float* __restrict__ out)
{
    const int bid = blockIdx.x;
    const int pg  = bid & 3;
    const int cg  = (bid >> 2) & 7;
    const int b   = bid >> 5;
    const int t   = threadIdx.x;

    const size_t chunk_off = ((size_t)b * Cn + (size_t)cg * 64) * HWn + pg * 1024;
    const float* xb = x + chunk_off;
    float* ob = out + chunk_off;

    const floatx4 msv = ((const floatx4*)(msF + (size_t)b * HWn + pg * 1024))[t];
    const float* mcRow = mcF + b * Cn + cg * 64;

#pragma unroll 8
    for (int r = 0; r < 64; ++r) {
        const floatx4 xv = ((const floatx4*)(xb + (size_t)r * HWn))[t];
        const floatx4 res = xv * (mcRow[r] * msv);
        __builtin_nontemporal_store(res, ((floatx4*)(ob + (size_t)r * HWn)) + t);
    }
}

extern "C" void kernel_launch(void* const* d_in, const int* in_sizes, int n_in,
                              void* d_out, int out_size, void* d_ws, size_t ws_size,
                              hipStream_t stream)
{
    const float* x     = (const float*)d_in[0];
    const float* w1    = (const float*)d_in[1];
    const float* w2    = (const float*)d_in[2];
    const float* wconv = (const float*)d_in[3];
    float* out = (float*)d_out;

    float* p = (float*)d_ws;
    float* cps  = p; p += NPG * Bn * Cn;   // 65536
    float* cpm  = p; p += NPG * Bn * Cn;   // 65536
    float* sps  = p; p += NCG * Bn * HWn;  // 1048576
    float* spm  = p; p += NCG * Bn * HWn;  // 1048576
    float* mcF  = p; p += Bn * Cn;         // 16384
    float* msF  = p; p += Bn * HWn;        // 131072

    hipLaunchKernelGGL(k1_reduce, dim3(Bn * NCG * NPG), dim3(256), 0, stream,
                       x, cps, cpm, sps, spm);
    hipLaunchKernelGGL(k_mid, dim3(Bn * 8), dim3(256), 0, stream,
                       sps, spm, cps, cpm, w1, w2, wconv, mcF, msF);
    hipLaunchKernelGGL(k4_apply, dim3(Bn * NCG * NPG), dim3(256), 0, stream,
                       x, mcF, msF, out);
}